// Round 1
// baseline (294.907 us; speedup 1.0000x reference)
//
#include <hip/hip_runtime.h>
#include <hip/hip_bf16.h>

// Problem constants
#define N_    4
#define C_    256
#define PS_   4096      // 64*64 source pixels
#define PO_   16384     // 128*128 output pixels
#define COMP_ 64
#define QCH_  100       // K*K*R*R

typedef unsigned short u16;
typedef __attribute__((ext_vector_type(8))) short short8;   // 8 bf16 = 4 VGPR
typedef __attribute__((ext_vector_type(4))) float f32x4;

__device__ __forceinline__ u16 f2bu(float f) {
    __hip_bfloat16 h = __float2bfloat16(f);
    return __builtin_bit_cast(u16, h);
}
__device__ __forceinline__ float bits2f(unsigned u) {
    union { unsigned i; float f; } v; v.i = u; return v.f;
}

// ---------------------------------------------------------------------------
// Kernel 0 (merged prep):
//  bid<256 : Weff_bf[o][c] = bf16( w_bott[o,:256]@w_conv2 + w_bott[o,256+c] ), beff
//  bid<544 : Wb[128 q][576 u] bf16 (pad q 100->128)
//  else    : Wcc_bf[64 m][256 c] bf16
__global__ __launch_bounds__(256) void k_prep(const float* __restrict__ w_bott,
        const float* __restrict__ w_conv2, const float* __restrict__ b_conv2,
        const float* __restrict__ w_ce, const float* __restrict__ w_cc,
        u16* __restrict__ Weff_bf, float* __restrict__ beff,
        u16* __restrict__ Wb, u16* __restrict__ Wcc_bf) {
    int bid = blockIdx.x;
    if (bid < 256) {
        int o = bid, c = threadIdx.x;
        __shared__ float wb[512];
        wb[c]       = w_bott[o * 512 + c];
        wb[c + 256] = w_bott[o * 512 + 256 + c];
        __syncthreads();
        float acc = wb[256 + c];
        #pragma unroll 8
        for (int m = 0; m < 256; ++m)
            acc += wb[m] * w_conv2[m * 256 + c];
        Weff_bf[o * 256 + c] = f2bu(acc);
        if (c == 0) {
            float be = 0.f;
            for (int m = 0; m < 256; ++m) be += wb[m] * b_conv2[m];
            beff[o] = be;
        }
    } else if (bid < 544) {
        int i = (bid - 256) * 256 + threadIdx.x;   // over 128*576
        int q = i / 576, u = i - q * 576;
        float v = (q < 100) ? w_ce[q * 576 + u] : 0.f;
        Wb[i] = f2bu(v);
    } else {
        int j = (bid - 544) * 256 + threadIdx.x;   // over 64*256
        Wcc_bf[j] = f2bu(w_cc[j]);
    }
}

// ---------------------------------------------------------------------------
// Kernel 1: channel compressor MFMA GEMM: M=64, K=256, N=64/block (256 blocks)
__global__ __launch_bounds__(256) void k_compress_mfma(const u16* __restrict__ Wcc_bf,
        const float* __restrict__ high, const float* __restrict__ b_cc,
        float* __restrict__ comp) {
    int tid = threadIdx.x;
    int wid = tid >> 6, lane = tid & 63;
    int col = lane & 15, quad = lane >> 4;
    int px0 = blockIdx.x * 64;
    int n = px0 >> 12, pxb = px0 & 4095;
    __shared__ u16 As[64 * 40];
    __shared__ u16 Bs[64 * 40];
    f32x4 acc[4] = {};
    #pragma unroll 1
    for (int k0 = 0; k0 < 256; k0 += 32) {
        __syncthreads();
        {   // A: 64 rows x 32 k
            int row = tid >> 2, seg = tid & 3;
            short8 av = *reinterpret_cast<const short8*>(Wcc_bf + row * 256 + k0 + seg * 8);
            *reinterpret_cast<short8*>(&As[row * 40 + seg * 8]) = av;
        }
        #pragma unroll
        for (int it = 0; it < 4; ++it) {   // B: 32 c x 64 px, transpose+cvt
            int idx = it * 256 + tid;       // 0..1023
            int c = (idx >> 6) * 2, px = idx & 63;
            const float* hp = high + (n * C_ + k0 + c) * PS_ + pxb + px;
            unsigned lo = f2bu(hp[0]);
            unsigned hi = f2bu(hp[PS_]);
            *reinterpret_cast<unsigned*>(&Bs[px * 40 + c]) = lo | (hi << 16);
        }
        __syncthreads();
        short8 a = *reinterpret_cast<const short8*>(&As[(wid * 16 + col) * 40 + quad * 8]);
        #pragma unroll
        for (int nt = 0; nt < 4; ++nt) {
            short8 b = *reinterpret_cast<const short8*>(&Bs[(nt * 16 + col) * 40 + quad * 8]);
            acc[nt] = __builtin_amdgcn_mfma_f32_16x16x32_bf16(a, b, acc[nt], 0, 0, 0);
        }
    }
    #pragma unroll
    for (int r = 0; r < 4; ++r) {
        int m = wid * 16 + quad * 4 + r;
        float bias = b_cc[m];
        float* cp = comp + (n * COMP_ + m) * PS_ + pxb + col;
        #pragma unroll
        for (int nt = 0; nt < 4; ++nt)
            cp[nt * 16] = acc[nt][r] + bias;
    }
}

// ---------------------------------------------------------------------------
// Kernel 2: im2col of comp -> Icol[gpx][576 u] bf16, zero-padded 3x3
__global__ __launch_bounds__(256) void k_im2col(const float* __restrict__ comp,
        u16* __restrict__ Icol) {
    int b = blockIdx.x;
    int n = b >> 6, tile = b & 63;
    int ty0 = (tile >> 3) << 3, tx0 = (tile & 7) << 3;
    int tid = threadIdx.x;
    __shared__ float ct[64 * 100];   // 64 ch x 10x10 halo tile
    for (int idx = tid; idx < 6400; idx += 256) {
        int cc = idx / 100, r = idx - cc * 100;
        int yy = ty0 - 1 + r / 10, xx = tx0 - 1 + (r % 10);
        float v = 0.f;
        if ((unsigned)yy < 64u && (unsigned)xx < 64u)
            v = comp[(n * COMP_ + cc) * PS_ + yy * 64 + xx];
        ct[idx] = v;
    }
    __syncthreads();
    int u0 = tid * 2, u1 = u0 + 1;
    int c0 = (unsigned)u0 / 9u, t0 = u0 - c0 * 9;
    int c1 = (unsigned)u1 / 9u, t1 = u1 - c1 * 9;
    int off0 = c0 * 100 + (t0 / 3) * 10 + (t0 % 3);
    int off1 = c1 * 100 + (t1 / 3) * 10 + (t1 % 3);
    int u2 = 512 + tid * 2, u3 = u2 + 1;   // only tid<32
    int c2 = (unsigned)u2 / 9u, t2 = u2 - c2 * 9;
    int c3 = (unsigned)u3 / 9u, t3 = u3 - c3 * 9;
    int off2 = c2 * 100 + (t2 / 3) * 10 + (t2 % 3);
    int off3 = c3 * 100 + (t3 / 3) * 10 + (t3 % 3);
    #pragma unroll 1
    for (int px = 0; px < 64; ++px) {
        int py = px >> 3, pxx = px & 7;
        int base = py * 10 + pxx;
        int gpx = n * PS_ + (ty0 + py) * 64 + tx0 + pxx;
        u16* dst = Icol + gpx * 576;
        unsigned lo = f2bu(ct[off0 + base]);
        unsigned hi = f2bu(ct[off1 + base]);
        *reinterpret_cast<unsigned*>(dst + u0) = lo | (hi << 16);
        if (tid < 32) {
            unsigned lo2 = f2bu(ct[off2 + base]);
            unsigned hi2 = f2bu(ct[off3 + base]);
            *reinterpret_cast<unsigned*>(dst + u2) = lo2 | (hi2 << 16);
        }
    }
}

// ---------------------------------------------------------------------------
// Kernel 3: encoder MFMA GEMM: M=128(pad 100), K=576, N=64/block (256 blocks)
__global__ __launch_bounds__(256) void k_encode_mfma(const u16* __restrict__ Wb,
        const u16* __restrict__ Icol, const float* __restrict__ b_ce,
        float* __restrict__ mask_raw) {
    int tid = threadIdx.x;
    int wid = tid >> 6, lane = tid & 63;
    int col = lane & 15, quad = lane >> 4;
    int px0 = blockIdx.x * 64;
    int n = px0 >> 12, pxb = px0 & 4095;
    __shared__ u16 As[128 * 40];
    __shared__ u16 Bs[64 * 40];
    f32x4 acc[2][4] = {};
    #pragma unroll 1
    for (int k0 = 0; k0 < 576; k0 += 32) {
        __syncthreads();
        #pragma unroll
        for (int it = 0; it < 2; ++it) {   // A: 128 rows x 4 segs
            int s = tid + it * 256;
            int row = s >> 2, seg = s & 3;
            short8 av = *reinterpret_cast<const short8*>(Wb + row * 576 + k0 + seg * 8);
            *reinterpret_cast<short8*>(&As[row * 40 + seg * 8]) = av;
        }
        {   // B: 64 rows x 4 segs
            int row = tid >> 2, seg = tid & 3;
            short8 bv = *reinterpret_cast<const short8*>(Icol + (px0 + row) * 576 + k0 + seg * 8);
            *reinterpret_cast<short8*>(&Bs[row * 40 + seg * 8]) = bv;
        }
        __syncthreads();
        short8 a0 = *reinterpret_cast<const short8*>(&As[(wid * 32 + col) * 40 + quad * 8]);
        short8 a1 = *reinterpret_cast<const short8*>(&As[(wid * 32 + 16 + col) * 40 + quad * 8]);
        #pragma unroll
        for (int nt = 0; nt < 4; ++nt) {
            short8 b = *reinterpret_cast<const short8*>(&Bs[(nt * 16 + col) * 40 + quad * 8]);
            acc[0][nt] = __builtin_amdgcn_mfma_f32_16x16x32_bf16(a0, b, acc[0][nt], 0, 0, 0);
            acc[1][nt] = __builtin_amdgcn_mfma_f32_16x16x32_bf16(a1, b, acc[1][nt], 0, 0, 0);
        }
    }
    #pragma unroll
    for (int mi = 0; mi < 2; ++mi) {
        int qbase = (wid * 2 + mi) * 16 + quad * 4;
        #pragma unroll
        for (int r = 0; r < 4; ++r) {
            int q = qbase + r;
            if (q < 100) {
                float bias = b_ce[q];
                float* mp = mask_raw + (n * QCH_ + q) * PS_ + pxb + col;
                #pragma unroll
                for (int nt = 0; nt < 4; ++nt)
                    mp[nt * 16] = acc[mi][nt][r] + bias;
            }
        }
    }
}

// ---------------------------------------------------------------------------
// Kernel 4: Y GEMM MFMA: M=256, K=256, N=16384. Output Yt[gpx][256 ch] BF16.
__global__ __launch_bounds__(256) void k_ygemm_mfma(const u16* __restrict__ Weff_bf,
        const float* __restrict__ high, u16* __restrict__ Yt) {
    int tid = threadIdx.x;
    int wid = tid >> 6, lane = tid & 63;
    int col = lane & 15, quad = lane >> 4;
    int px0 = blockIdx.x * 128;
    int o0 = blockIdx.y * 128;
    int n = px0 >> 12, pxb = px0 & 4095;
    __shared__ u16 As[128 * 40];
    __shared__ u16 Bs[128 * 40];
    f32x4 acc[2][8] = {};
    #pragma unroll 1
    for (int k0 = 0; k0 < 256; k0 += 32) {
        __syncthreads();
        #pragma unroll
        for (int it = 0; it < 2; ++it) {
            int s = tid + it * 256;
            int row = s >> 2, seg = s & 3;
            short8 av = *reinterpret_cast<const short8*>(Weff_bf + (o0 + row) * 256 + k0 + seg * 8);
            *reinterpret_cast<short8*>(&As[row * 40 + seg * 8]) = av;
        }
        #pragma unroll
        for (int it = 0; it < 8; ++it) {
            int idx = it * 256 + tid;           // 0..2047
            int c = (idx >> 7) * 2, px = idx & 127;
            const float* hp = high + (n * C_ + k0 + c) * PS_ + pxb + px;
            unsigned lo = f2bu(hp[0]);
            unsigned hi = f2bu(hp[PS_]);
            *reinterpret_cast<unsigned*>(&Bs[px * 40 + c]) = lo | (hi << 16);
        }
        __syncthreads();
        short8 a0 = *reinterpret_cast<const short8*>(&As[(wid * 32 + col) * 40 + quad * 8]);
        short8 a1 = *reinterpret_cast<const short8*>(&As[(wid * 32 + 16 + col) * 40 + quad * 8]);
        #pragma unroll
        for (int nt = 0; nt < 8; ++nt) {
            short8 b = *reinterpret_cast<const short8*>(&Bs[(nt * 16 + col) * 40 + quad * 8]);
            acc[0][nt] = __builtin_amdgcn_mfma_f32_16x16x32_bf16(a0, b, acc[0][nt], 0, 0, 0);
            acc[1][nt] = __builtin_amdgcn_mfma_f32_16x16x32_bf16(a1, b, acc[1][nt], 0, 0, 0);
        }
    }
    #pragma unroll
    for (int mi = 0; mi < 2; ++mi) {
        int ob = o0 + wid * 32 + mi * 16 + quad * 4;
        #pragma unroll
        for (int nt = 0; nt < 8; ++nt) {
            int gpx = px0 + nt * 16 + col;
            unsigned lo = f2bu(acc[mi][nt][0]) | ((unsigned)f2bu(acc[mi][nt][1]) << 16);
            unsigned hi = f2bu(acc[mi][nt][2]) | ((unsigned)f2bu(acc[mi][nt][3]) << 16);
            uint2 pk; pk.x = lo; pk.y = hi;
            *reinterpret_cast<uint2*>(Yt + (size_t)gpx * 256 + ob) = pk;
        }
    }
}

// ---------------------------------------------------------------------------
// Kernel 5 v2: CARAFE reassembly, latency-optimized.
// grid (64 tiles, 4 n, 4 ch-quarters); 256 thr = 64 src px x {2 subpix-pair x 2 ch-half}.
// - softmax weights read directly from global (wave-coalesced, L1-shared) -> no mask LDS
// - vs[2][25] instead of vs[4][25] -> VGPR fits 4 waves/SIMD
// - fused BN partial sums (per-channel Sx, Sx^2) -> k_stats shrinks 64MB->1MB
__global__ __launch_bounds__(256, 4) void k_carafe(const u16* __restrict__ Yt,
        const float* __restrict__ mask_raw, const float* __restrict__ beff,
        float* __restrict__ xout, float* __restrict__ ps, float* __restrict__ pq) {
    int tile = blockIdx.x, n = blockIdx.y, zq = blockIdx.z;
    int sh0 = (tile >> 3) << 3, sw0 = (tile & 7) << 3;
    int tid = threadIdx.x;
    int px = tid & 63, g = tid >> 6;
    int ly = px >> 3, lx = px & 7;
    int h = sh0 + ly, w = sw0 + lx;
    int sp = (g & 1) << 1;        // subpixel pair: {0,1} or {2,3}
    int cg = (g >> 1) << 5;       // 32-ch half within this quarter
    int ch0 = zq << 6;            // 64-ch quarter base

    __shared__ u16 xt[144 * 68];  // 12x12 halo px x 64 ch (pad 68)  = 19584 B

    // stage Yt halo for this channel quarter (overlaps with mask loads below)
    const u16* Yb = Yt + (size_t)n * PS_ * 256;
    for (int idx = tid; idx < 1152; idx += 256) {
        int spix = idx >> 3, seg = idx & 7;
        int row = spix / 12, colm = spix - row * 12;
        int yy = sh0 - 2 + row, xx = sw0 - 2 + colm;
        short8 val = {};
        if ((unsigned)yy < 64u && (unsigned)xx < 64u)
            val = *reinterpret_cast<const short8*>(Yb + (size_t)(yy * 64 + xx) * 256 + ch0 + seg * 8);
        *reinterpret_cast<short8*>(&xt[spix * 68 + seg * 8]) = val;
    }

    // softmax over 25 taps for this thread's 2 subpixels, straight from global
    float vs[2][25];
    {
        const float* mb = mask_raw + ((size_t)n * QCH_ + sp) * PS_ + h * 64 + w;
        #pragma unroll
        for (int j = 0; j < 2; ++j) {
            #pragma unroll
            for (int k = 0; k < 25; ++k)
                vs[j][k] = mb[(size_t)(k * 4 + j) * PS_];
            float mx = vs[j][0];
            #pragma unroll
            for (int k = 1; k < 25; ++k) mx = fmaxf(mx, vs[j][k]);
            float sum = 0.f;
            #pragma unroll
            for (int k = 0; k < 25; ++k) { vs[j][k] = __expf(vs[j][k] - mx); sum += vs[j][k]; }
            float inv = 1.f / sum;
            #pragma unroll
            for (int k = 0; k < 25; ++k) vs[j][k] *= inv;
        }
    }
    __syncthreads();

    const u16* bp = xt + (ly * 12 + lx) * 68;
    int row_off = (2 * h + (sp >> 1)) * 128 + 2 * w;
    int slot = (n * 64 + tile) * 2 + (g & 1);
    float* hp_base = xout + (size_t)n * C_ * PO_;

    #pragma unroll 1
    for (int cq = 0; cq < 8; ++cq) {
        int c = cg + cq * 4;
        int ch = ch0 + c;
        f32x4 bv = *reinterpret_cast<const f32x4*>(beff + ch);
        float a0[4] = {bv[0], bv[1], bv[2], bv[3]};
        float a1[4] = {bv[0], bv[1], bv[2], bv[3]};
        const u16* tp = bp + c;
        #pragma unroll
        for (int ky = 0; ky < 5; ++ky) {
            #pragma unroll
            for (int kx = 0; kx < 5; ++kx) {
                uint2 rv = *reinterpret_cast<const uint2*>(tp + (ky * 12 + kx) * 68);
                float f0 = bits2f(rv.x << 16);
                float f1 = bits2f(rv.x & 0xffff0000u);
                float f2 = bits2f(rv.y << 16);
                float f3 = bits2f(rv.y & 0xffff0000u);
                int k = ky * 5 + kx;
                float m0 = vs[0][k], m1 = vs[1][k];
                a0[0] += m0 * f0; a0[1] += m0 * f1;
                a0[2] += m0 * f2; a0[3] += m0 * f3;
                a1[0] += m1 * f0; a1[1] += m1 * f1;
                a1[2] += m1 * f2; a1[3] += m1 * f3;
            }
        }
        // write: 2 adjacent output pixels per channel (row 2h+(sp>>1), cols 2w,2w+1)
        #pragma unroll
        for (int i = 0; i < 4; ++i) {
            float2 r; r.x = a0[i]; r.y = a1[i];
            *reinterpret_cast<float2*>(hp_base + (size_t)(ch + i) * PO_ + row_off) = r;
        }
        // fused BN partial sums: wave-reduce 64 lanes x 2 subpix per channel
        #pragma unroll
        for (int i = 0; i < 4; ++i) {
            float s  = a0[i] + a1[i];
            float q2 = a0[i] * a0[i] + a1[i] * a1[i];
            #pragma unroll
            for (int off = 1; off < 64; off <<= 1) {
                s  += __shfl_xor(s, off);
                q2 += __shfl_xor(q2, off);
            }
            if (px == 0) {
                ps[(ch + i) * 512 + slot] = s;
                pq[(ch + i) * 512 + slot] = q2;
            }
        }
    }
}

// ---------------------------------------------------------------------------
// Kernel 6 v2: reduce 512 partial sums per channel -> scale/shift (1 MB read)
__global__ __launch_bounds__(256) void k_stats(const float* __restrict__ ps,
        const float* __restrict__ pq, const float* __restrict__ gamma,
        const float* __restrict__ beta, float* __restrict__ scale,
        float* __restrict__ shift) {
    int o = blockIdx.x, tid = threadIdx.x;
    float s = ps[o * 512 + tid] + ps[o * 512 + 256 + tid];
    float q = pq[o * 512 + tid] + pq[o * 512 + 256 + tid];
    __shared__ float rs[256], rq[256];
    rs[tid] = s; rq[tid] = q;
    __syncthreads();
    for (int off = 128; off > 0; off >>= 1) {
        if (tid < off) { rs[tid] += rs[tid + off]; rq[tid] += rq[tid + off]; }
        __syncthreads();
    }
    if (tid == 0) {
        float mean = rs[0] * (1.f / 65536.f);
        float var  = rq[0] * (1.f / 65536.f) - mean * mean;
        float sc = rsqrtf(var + 1e-5f) * gamma[o];
        scale[o] = sc;
        shift[o] = beta[o] - mean * sc;
    }
}

// ---------------------------------------------------------------------------
// Kernel 7: in-place normalize + ReLU on d_out (f32), 4 elems/thread
__global__ __launch_bounds__(256) void k_norm(float* __restrict__ xb,
        const float* __restrict__ scale, const float* __restrict__ shift) {
    int base = (blockIdx.x * 256 + threadIdx.x) * 4;
    int o = (base >> 14) & 255;
    float sc = scale[o], sh = shift[o];
    float4 v = *reinterpret_cast<const float4*>(xb + base);
    v.x = fmaxf(v.x * sc + sh, 0.f);
    v.y = fmaxf(v.y * sc + sh, 0.f);
    v.z = fmaxf(v.z * sc + sh, 0.f);
    v.w = fmaxf(v.w * sc + sh, 0.f);
    *reinterpret_cast<float4*>(xb + base) = v;
}

// ---------------------------------------------------------------------------
extern "C" void kernel_launch(void* const* d_in, const int* in_sizes, int n_in,
                              void* d_out, int out_size, void* d_ws, size_t ws_size,
                              hipStream_t stream) {
    const float* high    = (const float*)d_in[1];
    const float* w_cc    = (const float*)d_in[2];
    const float* b_cc    = (const float*)d_in[3];
    const float* w_ce    = (const float*)d_in[4];
    const float* b_ce    = (const float*)d_in[5];
    const float* w_conv2 = (const float*)d_in[6];
    const float* b_conv2 = (const float*)d_in[7];
    const float* w_bott  = (const float*)d_in[8];
    const float* gamma   = (const float*)d_in[9];
    const float* beta    = (const float*)d_in[10];

    char* ws = (char*)d_ws;
    float* beff    = (float*)(ws + 0);
    float* scale   = (float*)(ws + 1024);
    float* shift   = (float*)(ws + 2048);
    u16*   Weff_bf = (u16*)  (ws + 3072);        // 131072 B
    u16*   Wcc_bf  = (u16*)  (ws + 134144);      // 32768 B
    u16*   Wb      = (u16*)  (ws + 166912);      // 147456 B
    float* mask    = (float*)(ws + 314368);      // 6.55 MB (comp aliased: comp dead before encode writes)
    float* comp    = (float*)(ws + 314368);      // 4 MB
    u16*   Icol    = (u16*)  (ws + 6867968);     // 18.9 MB (dead after encode)
    u16*   Yt      = (u16*)  (ws + 6867968);     // 8.4 MB bf16, aliases Icol head
    float* ps      = (float*)(ws + 15256576);    // 512 KB, aliases Icol tail (dead)
    float* pq      = (float*)(ws + 15780864);    // 512 KB
    float* xout    = (float*)d_out;              // pre-BN x, normalized in place

    k_prep         <<<608, 256, 0, stream>>>(w_bott, w_conv2, b_conv2, w_ce, w_cc,
                                             Weff_bf, beff, Wb, Wcc_bf);
    k_compress_mfma<<<256, 256, 0, stream>>>(Wcc_bf, high, b_cc, comp);
    k_im2col       <<<256, 256, 0, stream>>>(comp, Icol);
    k_encode_mfma  <<<256, 256, 0, stream>>>(Wb, Icol, b_ce, mask);
    k_ygemm_mfma   <<<dim3(128, 2), 256, 0, stream>>>(Weff_bf, high, Yt);
    k_carafe       <<<dim3(64, 4, 4), 256, 0, stream>>>(Yt, mask, beff, xout, ps, pq);
    k_stats        <<<256, 256, 0, stream>>>(ps, pq, gamma, beta, scale, shift);
    k_norm         <<<16384, 256, 0, stream>>>(xout, scale, shift);
}